// Round 2
// baseline (21757.993 us; speedup 1.0000x reference)
//
#include <hip/hip_runtime.h>
#include <cstdio>
#include <cstdint>

typedef unsigned short u16;
typedef unsigned int u32;
typedef float f32x4 __attribute__((ext_vector_type(4)));
typedef short s16x8 __attribute__((ext_vector_type(8)));

#define DI __device__ __forceinline__

// problem sizes
#define BATCH 32
#define SEQT 512
#define HDIM 1024
#define PDIM 512
#define DEMB 512
#define G4H 4096
#define NWGR 256  // workgroups in the persistent recurrence kernel

// ---------------- bf16 helpers (RNE + hi/lo split) ----------------
DI u16 f2bf(float f) {
  u32 u = __float_as_uint(f);
  return (u16)((u + 0x7fffu + ((u >> 16) & 1u)) >> 16);
}
DI float bf2f(u16 h) { return __uint_as_float(((u32)h) << 16); }
DI void split2(float f, u16 &hi, u16 &lo) {
  hi = f2bf(f);
  lo = f2bf(f - bf2f(hi));  // exact residual capture to ~2^-17 rel
}
DI f32x4 mfma16(s16x8 a, s16x8 b, f32x4 c) {
  return __builtin_amdgcn_mfma_f32_16x16x32_bf16(a, b, c, 0, 0, 0);
}
DI void dma16(const void *g, void *l) {
  __builtin_amdgcn_global_load_lds((const __attribute__((address_space(1))) void *)g,
                                   (__attribute__((address_space(3))) void *)l, 16, 0, 0);
}

// ---------------- embed gather -> x0 hi/lo planes ----------------
__global__ void k_gather_pack(const int *__restrict__ tokens, const float *__restrict__ embed,
                              u16 *__restrict__ xhi, u16 *__restrict__ xlo) {
  int idx = blockIdx.x * 256 + threadIdx.x;  // one thread per 8 elements
  int m = idx >> 6;                          // row 0..16383 (m = b*T + t)
  int k8 = (idx & 63) << 3;
  int tok = tokens[m];
  const float *src = embed + (size_t)tok * DEMB + k8;
  float4 a = *(const float4 *)src;
  float4 b = *(const float4 *)(src + 4);
  float v[8] = {a.x, a.y, a.z, a.w, b.x, b.y, b.z, b.w};
  union UV { u16 h[8]; int4 v; };
  UV uh, ul;
#pragma unroll
  for (int j = 0; j < 8; ++j) split2(v[j], uh.h[j], ul.h[j]);
  size_t o = (size_t)m * DEMB + k8;
  *(int4 *)(xhi + o) = uh.v;
  *(int4 *)(xlo + o) = ul.v;
}

// ------- transpose+split weights: W[K][N] f32 -> T[N][K] bf16 hi/lo -------
__global__ void k_packT(const float *__restrict__ W, u16 *__restrict__ Thi, u16 *__restrict__ Tlo,
                        int K, int N) {
  __shared__ float tile[32][33];
  int n0 = blockIdx.x * 32, k0 = blockIdx.y * 32;
  int tx = threadIdx.x, ty = threadIdx.y;  // (32,8)
#pragma unroll
  for (int i = 0; i < 4; ++i) tile[ty + 8 * i][tx] = W[(size_t)(k0 + ty + 8 * i) * N + n0 + tx];
  __syncthreads();
#pragma unroll
  for (int i = 0; i < 4; ++i) {
    int n = ty + 8 * i;
    u16 hi, lo;
    split2(tile[tx][n], hi, lo);
    size_t o = (size_t)(n0 + n) * K + k0 + tx;
    Thi[o] = hi;
    Tlo[o] = lo;
  }
}

// ---------------- generic bf16x3 GEMM ----------------
// C[M][N] = A[M][K] * B^T-source[N][K] + bias, A/B given as bf16 hi/lo planes.
// 128x128 tile, BK=64, 4 waves. Both tiles DMA-staged via global_load_lds(16)
// into XOR-swizzled LDS (swizzle folded into per-lane SOURCE address).
// OM: 0 = bf16 out, 1 = hi/lo split out, 2 = f32 out scattered to (B,T,P).
template <int OM>
__global__ __launch_bounds__(256, 2) void k_gemm(const u16 *__restrict__ Ahi, const u16 *__restrict__ Alo,
                                                 const u16 *__restrict__ Bhi, const u16 *__restrict__ Blo,
                                                 const float *__restrict__ bias, void *__restrict__ out0,
                                                 void *__restrict__ out1, int M, int N, int K) {
  __shared__ u16 sP[4][128 * 64];  // planes: Ahi, Alo, Bhi, Blo (16KB each)
  const int tid = threadIdx.x;
  const int w = tid >> 6, lane = tid & 63;
  const int la15 = lane & 15, la4 = lane >> 4;
  const int nbn = N >> 7;
  const int bm = blockIdx.x / nbn, bn = blockIdx.x % nbn;
  const u16 *src = (w == 0) ? Ahi : (w == 1) ? Alo : (w == 2) ? Bhi : Blo;
  const int rowbase = (w < 2) ? bm * 128 : bn * 128;
  char *lds = (char *)&sP[w][0];

  f32x4 acc[2][8] = {};
  for (int kb = 0; kb < K; kb += 64) {
#pragma unroll
    for (int i = 0; i < 16; ++i) {
      int s = i * 64 + lane;            // 16B slot id
      int row = s >> 3;                 // 8 slots per 128B row
      int k16 = (s & 7) ^ (row & 7);    // inverse of read swizzle
      dma16(src + (size_t)(rowbase + row) * K + kb + k16 * 8, lds + i * 1024);
    }
    asm volatile("s_waitcnt vmcnt(0)" ::: "memory");
    __syncthreads();
#pragma unroll
    for (int ksl = 0; ksl < 2; ++ksl) {
      s16x8 ah[2], al[2];
#pragma unroll
      for (int rf = 0; rf < 2; ++rf) {
        int row = 32 * w + 16 * rf + la15;
        int slot = row * 8 + ((4 * ksl + la4) ^ (row & 7));
        ah[rf] = *(const s16x8 *)((const char *)&sP[0][0] + slot * 16);
        al[rf] = *(const s16x8 *)((const char *)&sP[1][0] + slot * 16);
      }
#pragma unroll
      for (int cf = 0; cf < 8; ++cf) {
        int col = 16 * cf + la15;
        int slot = col * 8 + ((4 * ksl + la4) ^ (col & 7));
        s16x8 bh = *(const s16x8 *)((const char *)&sP[2][0] + slot * 16);
        s16x8 bl = *(const s16x8 *)((const char *)&sP[3][0] + slot * 16);
#pragma unroll
        for (int rf = 0; rf < 2; ++rf) {
          acc[rf][cf] = mfma16(ah[rf], bh, acc[rf][cf]);
          acc[rf][cf] = mfma16(ah[rf], bl, acc[rf][cf]);
          acc[rf][cf] = mfma16(al[rf], bh, acc[rf][cf]);
        }
      }
    }
    __syncthreads();
  }
  // epilogue: D[r][c], r = 4*(lane>>4)+q (M), c = lane&15 (N)  [m89-verified]
#pragma unroll
  for (int rf = 0; rf < 2; ++rf) {
#pragma unroll
    for (int cf = 0; cf < 8; ++cf) {
      int c = bn * 128 + 16 * cf + la15;
      float bv = bias ? bias[c] : 0.f;
#pragma unroll
      for (int q = 0; q < 4; ++q) {
        int r = bm * 128 + 32 * w + 16 * rf + 4 * la4 + q;
        float v = acc[rf][cf][q] + bv;
        if (OM == 0) {
          ((u16 *)out0)[(size_t)r * N + c] = f2bf(v);
        } else if (OM == 1) {
          u16 hi, lo;
          split2(v, hi, lo);
          ((u16 *)out0)[(size_t)r * N + c] = hi;
          ((u16 *)out1)[(size_t)r * N + c] = lo;
        } else {
          int b2 = r & 31, tt = r >> 5;  // A rows are m = t*32 + b
          ((float *)out0)[((size_t)b2 * SEQT + tt) * PDIM + c] = v;
        }
      }
    }
  }
}

// ---------------- persistent LSTM recurrence ----------------
// 256 WGs x 256 threads, 1 WG/CU. WG = (rg = wg&1: 16 batch rows,
// g = wg>>1: 8 h-cols => 32 z-cols {i,f,g,o}x8). Wh slice (hi/lo, swizzled)
// resident in LDS for all 512 steps.
// Handshake (R2): store/poll, no RMW. Producer: one release-store per WG to
// done[t*256+wg] (16 distinct lines, no bouncing). Consumer: EACH WAVE
// independently polls all 256 words (lane l reads l,l+64,l+128,l+192) and
// proceeds on its own — no cross-wave barrier on the detection path.
__global__ __launch_bounds__(256, 1) void k_recur(const u16 *__restrict__ xz, const float *__restrict__ Wh,
                                                  u16 *hhi, u16 *hlo, int *done, int rowmode) {
  __shared__ u16 sW[2][32 * 1024];   // 128 KiB: [zc][k] u16, swizzled
  __shared__ float zacc[4][16][33];  // per-wave K-partials (+1 col pad)
  __shared__ float sC[128];          // cell state c[16 rows][8 cols]
  const int tid = threadIdx.x;
  const int w = tid >> 6, lane = tid & 63;
  const int la15 = lane & 15, la4 = lane >> 4;
  const int wg = blockIdx.x;
  const int rg = wg & 1;
  const int g = wg >> 1;

  // stage Wh column-slice, split hi/lo, swizzled (once per launch)
  for (int idx = tid; idx < 32 * 1024; idx += 256) {
    int zc = idx & 31;
    int k = idx >> 5;
    int gate = zc >> 3, cl = zc & 7;
    int gcol = gate * HDIM + 8 * g + cl;
    u16 hi, lo;
    split2(Wh[(size_t)k * G4H + gcol], hi, lo);
    int boff = zc * 2048 + ((((k >> 3) ^ (zc & 7))) << 4) + (k & 7) * 2;
    *(u16 *)((char *)&sW[0][0] + boff) = hi;
    *(u16 *)((char *)&sW[1][0] + boff) = lo;
  }
  if (tid < 128) sC[tid] = 0.f;
  __syncthreads();

  const int r_g = tid >> 3, hc = tid & 7;  // gate-phase coords (tid<128)
  const int bg = 16 * rg + r_g;
  const int ks0 = 8 * w;         // this wave's k-slice range
  const int bA = 16 * rg + la15; // A-operand batch row

  for (int t = 0; t < SEQT; ++t) {
    // prefetch xz for this step (independent of h; hides under poll)
    float xzv[4] = {0.f, 0.f, 0.f, 0.f};
    if (tid < 128) {
      size_t m = (rowmode == 0) ? ((size_t)bg * SEQT + t) : ((size_t)t * 32 + bg);
      const u16 *px = xz + m * G4H + 8 * g + hc;
#pragma unroll
      for (int gi = 0; gi < 4; ++gi) xzv[gi] = bf2f(px[(size_t)gi * HDIM]);
    }
    if (t > 0) {
      // per-wave poll: all 64 lanes cover the 256 done-words
      {
        const int *dp = done + (size_t)(t - 1) * 256 + lane;
        for (long tries = 0;; ++tries) {
          int a = __hip_atomic_load(dp, __ATOMIC_RELAXED, __HIP_MEMORY_SCOPE_AGENT);
          int b = __hip_atomic_load(dp + 64, __ATOMIC_RELAXED, __HIP_MEMORY_SCOPE_AGENT);
          int c = __hip_atomic_load(dp + 128, __ATOMIC_RELAXED, __HIP_MEMORY_SCOPE_AGENT);
          int d = __hip_atomic_load(dp + 192, __ATOMIC_RELAXED, __HIP_MEMORY_SCOPE_AGENT);
          if (__all((a & b & c & d) == 1)) break;
          if (tries > (1L << 22)) break;  // safety valve, never hit when co-resident
          __builtin_amdgcn_s_sleep(1);
        }
        __builtin_amdgcn_fence(__ATOMIC_ACQUIRE, "agent");  // L1/L2 inv (cross-XCD)
      }
      // z-slice partial: A = h[t-1] rows (global, hi/lo), B = sW (LDS)
      const u16 *ph = hhi + ((size_t)(t - 1) * 32 + bA) * HDIM;
      const u16 *pl = hlo + ((size_t)(t - 1) * 32 + bA) * HDIM;
      s16x8 ahi[8], alo[8];
#pragma unroll
      for (int j8 = 0; j8 < 8; ++j8) {
        int k = 32 * (ks0 + j8) + 8 * la4;
        ahi[j8] = *(const s16x8 *)(ph + k);
        alo[j8] = *(const s16x8 *)(pl + k);
      }
      f32x4 acc[2] = {};
#pragma unroll
      for (int j8 = 0; j8 < 8; ++j8) {
#pragma unroll
        for (int cf = 0; cf < 2; ++cf) {
          int zc = 16 * cf + la15;
          int slot = (4 * (ks0 + j8) + la4) ^ (zc & 7);
          int boff = zc * 2048 + (slot << 4);
          s16x8 bh = *(const s16x8 *)((const char *)&sW[0][0] + boff);
          s16x8 bl = *(const s16x8 *)((const char *)&sW[1][0] + boff);
          acc[cf] = mfma16(ahi[j8], bh, acc[cf]);
          acc[cf] = mfma16(ahi[j8], bl, acc[cf]);
          acc[cf] = mfma16(alo[j8], bh, acc[cf]);
        }
      }
#pragma unroll
      for (int cf = 0; cf < 2; ++cf)
#pragma unroll
        for (int q = 0; q < 4; ++q) zacc[w][4 * la4 + q][16 * cf + la15] = acc[cf][q];
    }
    __syncthreads();
    if (tid < 128) {
      float z4[4];
#pragma unroll
      for (int gi = 0; gi < 4; ++gi) {
        float s = xzv[gi];
        if (t > 0) {
          int zc = gi * 8 + hc;
          s += zacc[0][r_g][zc] + zacc[1][r_g][zc] + zacc[2][r_g][zc] + zacc[3][r_g][zc];
        }
        z4[gi] = s;
      }
      float ig = 1.f / (1.f + expf(-z4[0]));
      float fg = 1.f / (1.f + expf(-z4[1]));
      float gg = tanhf(z4[2]);
      float og = 1.f / (1.f + expf(-z4[3]));
      float c = fg * sC[tid] + ig * gg;
      sC[tid] = c;
      float h = og * tanhf(c);
      u16 hi, lo;
      split2(h, hi, lo);
      size_t ho = ((size_t)t * 32 + bg) * HDIM + 8 * g + hc;
      hhi[ho] = hi;
      hlo[ho] = lo;
    }
    __syncthreads();  // drains vmcnt; h-stores now in this XCD's L2
    if (tid == 0)
      __hip_atomic_store(done + (size_t)t * 256 + wg, 1, __ATOMIC_RELEASE, __HIP_MEMORY_SCOPE_AGENT);
  }
}

// ---------------- host launcher ----------------
extern "C" void kernel_launch(void *const *d_in, const int *in_sizes, int n_in,
                              void *d_out, int out_size, void *d_ws, size_t ws_size,
                              hipStream_t stream) {
  const int *tokens = (const int *)d_in[0];
  const float *embed = (const float *)d_in[1];
  const float *Wx0 = (const float *)d_in[2];
  const float *Wh0 = (const float *)d_in[3];
  const float *b0 = (const float *)d_in[4];
  const float *Wfc0 = (const float *)d_in[5];
  const float *bfc0 = (const float *)d_in[6];
  const float *Wx1 = (const float *)d_in[7];
  const float *Wh1 = (const float *)d_in[8];
  const float *b1 = (const float *)d_in[9];
  const float *Wfc1 = (const float *)d_in[10];
  const float *bfc1 = (const float *)d_in[11];

  constexpr size_t NEED = 255856640;  // ~244 MiB (unchanged from validated R1)
  if (ws_size < NEED) {
    fprintf(stderr, "RNNLM kernel: ws too small (%zu < %zu)\n", ws_size, NEED);
    return;
  }
  char *ws = (char *)d_ws;
  u16 *xz = (u16 *)(ws + 0);               // [16384][4096] bf16 (reused L0/L1)
  u16 *hhi = (u16 *)(ws + 134217728);      // [T][32][1024] (h0 then h1)
  u16 *hlo = (u16 *)(ws + 167772160);
  u16 *x1hi = (u16 *)(ws + 201326592);     // also x0hi (disjoint lifetimes)
  u16 *x1lo = (u16 *)(ws + 218103808);     // also x0lo
  u16 *WxT0hi = (u16 *)(ws + 234881024);
  u16 *WxT0lo = (u16 *)(ws + 239075328);
  u16 *WfcT0hi = (u16 *)(ws + 243269632);
  u16 *WfcT0lo = (u16 *)(ws + 244318208);
  u16 *WxT1hi = (u16 *)(ws + 245366784);
  u16 *WxT1lo = (u16 *)(ws + 249561088);
  u16 *WfcT1hi = (u16 *)(ws + 253755392);
  u16 *WfcT1lo = (u16 *)(ws + 254803968);
  // done flags: carved from WxT regions, which are DEAD once their xz-GEMM
  // has run. Zeroed mid-stream (hipMemsetAsync is graph-capturable).
  int *done0 = (int *)(ws + 234881024);    // overlaps WxT0hi (512 KB used)
  int *done1 = (int *)(ws + 245366784);    // overlaps WxT1hi (512 KB used)

  // weight prepack (transpose + hi/lo split)
  k_packT<<<dim3(G4H / 32, DEMB / 32), dim3(32, 8), 0, stream>>>(Wx0, WxT0hi, WxT0lo, DEMB, G4H);
  k_packT<<<dim3(PDIM / 32, HDIM / 32), dim3(32, 8), 0, stream>>>(Wfc0, WfcT0hi, WfcT0lo, HDIM, PDIM);
  k_packT<<<dim3(G4H / 32, DEMB / 32), dim3(32, 8), 0, stream>>>(Wx1, WxT1hi, WxT1lo, DEMB, G4H);
  k_packT<<<dim3(PDIM / 32, HDIM / 32), dim3(32, 8), 0, stream>>>(Wfc1, WfcT1hi, WfcT1lo, HDIM, PDIM);
  // x0 = embed[tokens], hi/lo split  (rows m = b*T + t)
  k_gather_pack<<<4096, 256, 0, stream>>>(tokens, embed, x1hi, x1lo);

  // xz0 = x0 @ Wx0 + b0  -> bf16
  k_gemm<0><<<dim3(128 * 32), 256, 0, stream>>>(x1hi, x1lo, WxT0hi, WxT0lo, b0, xz, nullptr,
                                                16384, G4H, DEMB);
  // WxT0 now dead -> zero done0 in its place
  hipMemsetAsync(done0, 0, SEQT * 256 * sizeof(int), stream);
  // layer-0 recurrence (xz rows m = b*T + t)
  {
    const u16 *a0 = xz; const float *a1 = Wh0; u16 *a2 = hhi; u16 *a3 = hlo; int *a4 = done0; int a5 = 0;
    void *args[] = {&a0, &a1, &a2, &a3, &a4, &a5};
    hipError_t e = hipLaunchCooperativeKernel((void *)k_recur, dim3(NWGR), dim3(256), args, 0, stream);
    if (e != hipSuccess) fprintf(stderr, "coop launch L0 failed: %d\n", (int)e);
  }
  // x1 = h0 @ Wfc0 + bfc0 -> hi/lo planes (rows m = t*32 + b)
  k_gemm<1><<<dim3(128 * 4), 256, 0, stream>>>(hhi, hlo, WfcT0hi, WfcT0lo, bfc0, x1hi, x1lo,
                                               16384, PDIM, HDIM);
  // xz1 = x1 @ Wx1 + b1 -> bf16
  k_gemm<0><<<dim3(128 * 32), 256, 0, stream>>>(x1hi, x1lo, WxT1hi, WxT1lo, b1, xz, nullptr,
                                                16384, G4H, DEMB);
  // WxT1 now dead -> zero done1 in its place
  hipMemsetAsync(done1, 0, SEQT * 256 * sizeof(int), stream);
  // layer-1 recurrence (xz rows m = t*32 + b)
  {
    const u16 *a0 = xz; const float *a1 = Wh1; u16 *a2 = hhi; u16 *a3 = hlo; int *a4 = done1; int a5 = 1;
    void *args[] = {&a0, &a1, &a2, &a3, &a4, &a5};
    hipError_t e = hipLaunchCooperativeKernel((void *)k_recur, dim3(NWGR), dim3(256), args, 0, stream);
    if (e != hipSuccess) fprintf(stderr, "coop launch L1 failed: %d\n", (int)e);
  }
  // out = h1 @ Wfc1 + bfc1 -> f32, scattered to (B,T,P)
  k_gemm<2><<<dim3(128 * 4), 256, 0, stream>>>(hhi, hlo, WfcT1hi, WfcT1lo, bfc1, d_out, nullptr,
                                               16384, PDIM, HDIM);
}

// Round 3
// 5585.601 us; speedup vs baseline: 3.8954x; 3.8954x over previous
//
#include <hip/hip_runtime.h>
#include <cstdio>
#include <cstdint>

typedef unsigned short u16;
typedef unsigned int u32;
typedef float f32x4 __attribute__((ext_vector_type(4)));
typedef short s16x8 __attribute__((ext_vector_type(8)));

#define DI __device__ __forceinline__

// problem sizes
#define BATCH 32
#define SEQT 512
#define HDIM 1024
#define PDIM 512
#define DEMB 512
#define G4H 4096
#define NWGR 256  // workgroups in the persistent recurrence kernel

// ---------------- bf16 helpers (RNE + hi/lo split) ----------------
DI u16 f2bf(float f) {
  u32 u = __float_as_uint(f);
  return (u16)((u + 0x7fffu + ((u >> 16) & 1u)) >> 16);
}
DI float bf2f(u16 h) { return __uint_as_float(((u32)h) << 16); }
DI void split2(float f, u16 &hi, u16 &lo) {
  hi = f2bf(f);
  lo = f2bf(f - bf2f(hi));  // exact residual capture to ~2^-17 rel
}
DI f32x4 mfma16(s16x8 a, s16x8 b, f32x4 c) {
  return __builtin_amdgcn_mfma_f32_16x16x32_bf16(a, b, c, 0, 0, 0);
}
DI void dma16(const void *g, void *l) {
  __builtin_amdgcn_global_load_lds((const __attribute__((address_space(1))) void *)g,
                                   (__attribute__((address_space(3))) void *)l, 16, 0, 0);
}
// device-scope (sc1) memory ops: bypass L1/L2, read/write the coherence point.
// No buffer_inv / buffer_wbl2 needed anywhere in the recurrence handshake.
DI s16x8 ld128_dev(const u16 *p) {
  s16x8 r;
  asm volatile("global_load_dwordx4 %0, %1, off sc1" : "=v"(r) : "v"(p));
  return r;
}
DI void st16_dev(u16 *p, u16 v) {
  asm volatile("global_store_short %0, %1, off sc1" ::"v"(p), "v"((u32)v) : "memory");
}
DI void st32_dev(int *p, int v) {
  asm volatile("global_store_dword %0, %1, off sc1" ::"v"(p), "v"(v) : "memory");
}

// ---------------- embed gather -> x0 hi/lo planes ----------------
__global__ void k_gather_pack(const int *__restrict__ tokens, const float *__restrict__ embed,
                              u16 *__restrict__ xhi, u16 *__restrict__ xlo) {
  int idx = blockIdx.x * 256 + threadIdx.x;  // one thread per 8 elements
  int m = idx >> 6;                          // row 0..16383 (m = b*T + t)
  int k8 = (idx & 63) << 3;
  int tok = tokens[m];
  const float *src = embed + (size_t)tok * DEMB + k8;
  float4 a = *(const float4 *)src;
  float4 b = *(const float4 *)(src + 4);
  float v[8] = {a.x, a.y, a.z, a.w, b.x, b.y, b.z, b.w};
  union UV { u16 h[8]; int4 v; };
  UV uh, ul;
#pragma unroll
  for (int j = 0; j < 8; ++j) split2(v[j], uh.h[j], ul.h[j]);
  size_t o = (size_t)m * DEMB + k8;
  *(int4 *)(xhi + o) = uh.v;
  *(int4 *)(xlo + o) = ul.v;
}

// ------- transpose+split weights: W[K][N] f32 -> T[N][K] bf16 hi/lo -------
__global__ void k_packT(const float *__restrict__ W, u16 *__restrict__ Thi, u16 *__restrict__ Tlo,
                        int K, int N) {
  __shared__ float tile[32][33];
  int n0 = blockIdx.x * 32, k0 = blockIdx.y * 32;
  int tx = threadIdx.x, ty = threadIdx.y;  // (32,8)
#pragma unroll
  for (int i = 0; i < 4; ++i) tile[ty + 8 * i][tx] = W[(size_t)(k0 + ty + 8 * i) * N + n0 + tx];
  __syncthreads();
#pragma unroll
  for (int i = 0; i < 4; ++i) {
    int n = ty + 8 * i;
    u16 hi, lo;
    split2(tile[tx][n], hi, lo);
    size_t o = (size_t)(n0 + n) * K + k0 + tx;
    Thi[o] = hi;
    Tlo[o] = lo;
  }
}

// ---------------- generic bf16x3 GEMM ----------------
// C[M][N] = A[M][K] * B^T-source[N][K] + bias, A/B given as bf16 hi/lo planes.
// 128x128 tile, BK=64, 4 waves. Both tiles DMA-staged via global_load_lds(16)
// into XOR-swizzled LDS (swizzle folded into per-lane SOURCE address).
// OM: 0 = bf16 out, 1 = hi/lo split out, 2 = f32 out scattered to (B,T,P).
template <int OM>
__global__ __launch_bounds__(256, 2) void k_gemm(const u16 *__restrict__ Ahi, const u16 *__restrict__ Alo,
                                                 const u16 *__restrict__ Bhi, const u16 *__restrict__ Blo,
                                                 const float *__restrict__ bias, void *__restrict__ out0,
                                                 void *__restrict__ out1, int M, int N, int K) {
  __shared__ u16 sP[4][128 * 64];  // planes: Ahi, Alo, Bhi, Blo (16KB each)
  const int tid = threadIdx.x;
  const int w = tid >> 6, lane = tid & 63;
  const int la15 = lane & 15, la4 = lane >> 4;
  const int nbn = N >> 7;
  const int bm = blockIdx.x / nbn, bn = blockIdx.x % nbn;
  const u16 *src = (w == 0) ? Ahi : (w == 1) ? Alo : (w == 2) ? Bhi : Blo;
  const int rowbase = (w < 2) ? bm * 128 : bn * 128;
  char *lds = (char *)&sP[w][0];

  f32x4 acc[2][8] = {};
  for (int kb = 0; kb < K; kb += 64) {
#pragma unroll
    for (int i = 0; i < 16; ++i) {
      int s = i * 64 + lane;            // 16B slot id
      int row = s >> 3;                 // 8 slots per 128B row
      int k16 = (s & 7) ^ (row & 7);    // inverse of read swizzle
      dma16(src + (size_t)(rowbase + row) * K + kb + k16 * 8, lds + i * 1024);
    }
    asm volatile("s_waitcnt vmcnt(0)" ::: "memory");
    __syncthreads();
#pragma unroll
    for (int ksl = 0; ksl < 2; ++ksl) {
      s16x8 ah[2], al[2];
#pragma unroll
      for (int rf = 0; rf < 2; ++rf) {
        int row = 32 * w + 16 * rf + la15;
        int slot = row * 8 + ((4 * ksl + la4) ^ (row & 7));
        ah[rf] = *(const s16x8 *)((const char *)&sP[0][0] + slot * 16);
        al[rf] = *(const s16x8 *)((const char *)&sP[1][0] + slot * 16);
      }
#pragma unroll
      for (int cf = 0; cf < 8; ++cf) {
        int col = 16 * cf + la15;
        int slot = col * 8 + ((4 * ksl + la4) ^ (col & 7));
        s16x8 bh = *(const s16x8 *)((const char *)&sP[2][0] + slot * 16);
        s16x8 bl = *(const s16x8 *)((const char *)&sP[3][0] + slot * 16);
#pragma unroll
        for (int rf = 0; rf < 2; ++rf) {
          acc[rf][cf] = mfma16(ah[rf], bh, acc[rf][cf]);
          acc[rf][cf] = mfma16(ah[rf], bl, acc[rf][cf]);
          acc[rf][cf] = mfma16(al[rf], bh, acc[rf][cf]);
        }
      }
    }
    __syncthreads();
  }
  // epilogue: D[r][c], r = 4*(lane>>4)+q (M), c = lane&15 (N)  [m89-verified]
#pragma unroll
  for (int rf = 0; rf < 2; ++rf) {
#pragma unroll
    for (int cf = 0; cf < 8; ++cf) {
      int c = bn * 128 + 16 * cf + la15;
      float bv = bias ? bias[c] : 0.f;
#pragma unroll
      for (int q = 0; q < 4; ++q) {
        int r = bm * 128 + 32 * w + 16 * rf + 4 * la4 + q;
        float v = acc[rf][cf][q] + bv;
        if (OM == 0) {
          ((u16 *)out0)[(size_t)r * N + c] = f2bf(v);
        } else if (OM == 1) {
          u16 hi, lo;
          split2(v, hi, lo);
          ((u16 *)out0)[(size_t)r * N + c] = hi;
          ((u16 *)out1)[(size_t)r * N + c] = lo;
        } else {
          int b2 = r & 31, tt = r >> 5;  // A rows are m = t*32 + b
          ((float *)out0)[((size_t)b2 * SEQT + tt) * PDIM + c] = v;
        }
      }
    }
  }
}

// ---------------- persistent LSTM recurrence ----------------
// 256 WGs x 256 threads, 1 WG/CU. WG = (rg = wg&1: 16 batch rows,
// g = wg>>1: 8 h-cols => 32 z-cols {i,f,g,o}x8). Wh slice (hi/lo, swizzled)
// resident in LDS for all 512 steps.
// Handshake (R3): manual coherence, ZERO cache-maintenance ops.
//  producer: h stored with sc1 (write-through to L3) -> per-wave
//            s_waitcnt vmcnt(0) -> __syncthreads -> one sc1 flag store/WG.
//  consumer: wave0 polls the 128 flags of its rg half (2 coalesced sc1
//            loads/lane) -> __syncthreads -> all waves load h via sc1
//            dwordx4 (bypass L1/L2: never stale) -> waitcnt + sched_barrier
//            (rule 18) -> MFMA. No buffer_inv / buffer_wbl2 per step.
__global__ __launch_bounds__(256, 1) void k_recur(const u16 *__restrict__ xz, const float *__restrict__ Wh,
                                                  u16 *hhi, u16 *hlo, int *done, int rowmode) {
  __shared__ u16 sW[2][32 * 1024];   // 128 KiB: [zc][k] u16, swizzled
  __shared__ float zacc[4][16][33];  // per-wave K-partials (+1 col pad)
  __shared__ float sC[128];          // cell state c[16 rows][8 cols]
  const int tid = threadIdx.x;
  const int w = tid >> 6, lane = tid & 63;
  const int la15 = lane & 15, la4 = lane >> 4;
  const int wg = blockIdx.x;
  const int rg = wg & 1;
  const int g = wg >> 1;

  // stage Wh column-slice, split hi/lo, swizzled (once per launch)
  for (int idx = tid; idx < 32 * 1024; idx += 256) {
    int zc = idx & 31;
    int k = idx >> 5;
    int gate = zc >> 3, cl = zc & 7;
    int gcol = gate * HDIM + 8 * g + cl;
    u16 hi, lo;
    split2(Wh[(size_t)k * G4H + gcol], hi, lo);
    int boff = zc * 2048 + ((((k >> 3) ^ (zc & 7))) << 4) + (k & 7) * 2;
    *(u16 *)((char *)&sW[0][0] + boff) = hi;
    *(u16 *)((char *)&sW[1][0] + boff) = lo;
  }
  if (tid < 128) sC[tid] = 0.f;
  __syncthreads();

  const int r_g = tid >> 3, hc = tid & 7;  // gate-phase coords (tid<128)
  const int bg = 16 * rg + r_g;
  const int ks0 = 8 * w;         // this wave's k-slice range
  const int bA = 16 * rg + la15; // A-operand batch row

  for (int t = 0; t < SEQT; ++t) {
    // prefetch xz for this step (normal loads; xz stays L2-cached — no invs)
    float xzv[4] = {0.f, 0.f, 0.f, 0.f};
    if (tid < 128) {
      size_t m = (rowmode == 0) ? ((size_t)bg * SEQT + t) : ((size_t)t * 32 + bg);
      const u16 *px = xz + m * G4H + 8 * g + hc;
#pragma unroll
      for (int gi = 0; gi < 4; ++gi) xzv[gi] = bf2f(px[(size_t)gi * HDIM]);
    }
    if (t > 0 && w == 0) {
      // wave0 polls the 128 producer flags of its rg half
      const int *dp = done + (size_t)(t - 1) * 256 + rg * 128 + lane;
      for (long tries = 0;; ++tries) {
        int a = __hip_atomic_load(dp, __ATOMIC_RELAXED, __HIP_MEMORY_SCOPE_AGENT);
        int b = __hip_atomic_load(dp + 64, __ATOMIC_RELAXED, __HIP_MEMORY_SCOPE_AGENT);
        if (__all((a & b) == 1)) break;
        if (tries > (1L << 22)) break;  // safety valve, never hit when co-resident
        __builtin_amdgcn_s_sleep(1);
      }
    }
    __syncthreads();  // h[t-1] globally visible once wave0's poll succeeded
    if (t > 0) {
      // z-slice partial: A = h[t-1] rows (L3 via sc1 loads), B = sW (LDS)
      const u16 *ph = hhi + ((size_t)(t - 1) * 32 + bA) * HDIM;
      const u16 *pl = hlo + ((size_t)(t - 1) * 32 + bA) * HDIM;
      s16x8 ahi[8], alo[8];
#pragma unroll
      for (int j8 = 0; j8 < 8; ++j8) {
        int k = 32 * (ks0 + j8) + 8 * la4;
        ahi[j8] = ld128_dev(ph + k);
        alo[j8] = ld128_dev(pl + k);
      }
      asm volatile("s_waitcnt vmcnt(0)" ::: "memory");
      __builtin_amdgcn_sched_barrier(0);  // rule 18: pin MFMA after the waitcnt
      f32x4 acc[2] = {};
#pragma unroll
      for (int j8 = 0; j8 < 8; ++j8) {
#pragma unroll
        for (int cf = 0; cf < 2; ++cf) {
          int zc = 16 * cf + la15;
          int slot = (4 * (ks0 + j8) + la4) ^ (zc & 7);
          int boff = zc * 2048 + (slot << 4);
          s16x8 bh = *(const s16x8 *)((const char *)&sW[0][0] + boff);
          s16x8 bl = *(const s16x8 *)((const char *)&sW[1][0] + boff);
          acc[cf] = mfma16(ahi[j8], bh, acc[cf]);
          acc[cf] = mfma16(ahi[j8], bl, acc[cf]);
          acc[cf] = mfma16(alo[j8], bh, acc[cf]);
        }
      }
#pragma unroll
      for (int cf = 0; cf < 2; ++cf)
#pragma unroll
        for (int q = 0; q < 4; ++q) zacc[w][4 * la4 + q][16 * cf + la15] = acc[cf][q];
    }
    __syncthreads();
    if (tid < 128) {
      float z4[4];
#pragma unroll
      for (int gi = 0; gi < 4; ++gi) {
        float s = xzv[gi];
        if (t > 0) {
          int zc = gi * 8 + hc;
          s += zacc[0][r_g][zc] + zacc[1][r_g][zc] + zacc[2][r_g][zc] + zacc[3][r_g][zc];
        }
        z4[gi] = s;
      }
      float ig = 1.f / (1.f + expf(-z4[0]));
      float fg = 1.f / (1.f + expf(-z4[1]));
      float gg = tanhf(z4[2]);
      float og = 1.f / (1.f + expf(-z4[3]));
      float c = fg * sC[tid] + ig * gg;
      sC[tid] = c;
      float h = og * tanhf(c);
      u16 hi, lo;
      split2(h, hi, lo);
      size_t ho = ((size_t)t * 32 + bg) * HDIM + 8 * g + hc;
      st16_dev(hhi + ho, hi);   // sc1: write-through to coherence point
      st16_dev(hlo + ho, lo);
    }
    asm volatile("s_waitcnt vmcnt(0)" ::: "memory");  // own h-stores at L3
    __syncthreads();                                  // all waves' stores done
    if (tid == 0) st32_dev(done + (size_t)t * 256 + rg * 128 + g, 1);
  }
}

// ---------------- host launcher ----------------
extern "C" void kernel_launch(void *const *d_in, const int *in_sizes, int n_in,
                              void *d_out, int out_size, void *d_ws, size_t ws_size,
                              hipStream_t stream) {
  const int *tokens = (const int *)d_in[0];
  const float *embed = (const float *)d_in[1];
  const float *Wx0 = (const float *)d_in[2];
  const float *Wh0 = (const float *)d_in[3];
  const float *b0 = (const float *)d_in[4];
  const float *Wfc0 = (const float *)d_in[5];
  const float *bfc0 = (const float *)d_in[6];
  const float *Wx1 = (const float *)d_in[7];
  const float *Wh1 = (const float *)d_in[8];
  const float *b1 = (const float *)d_in[9];
  const float *Wfc1 = (const float *)d_in[10];
  const float *bfc1 = (const float *)d_in[11];

  constexpr size_t NEED = 255856640;  // ~244 MiB (unchanged from validated R1)
  if (ws_size < NEED) {
    fprintf(stderr, "RNNLM kernel: ws too small (%zu < %zu)\n", ws_size, NEED);
    return;
  }
  char *ws = (char *)d_ws;
  u16 *xz = (u16 *)(ws + 0);               // [16384][4096] bf16 (reused L0/L1)
  u16 *hhi = (u16 *)(ws + 134217728);      // [T][32][1024] (h0 then h1)
  u16 *hlo = (u16 *)(ws + 167772160);
  u16 *x1hi = (u16 *)(ws + 201326592);     // also x0hi (disjoint lifetimes)
  u16 *x1lo = (u16 *)(ws + 218103808);     // also x0lo
  u16 *WxT0hi = (u16 *)(ws + 234881024);
  u16 *WxT0lo = (u16 *)(ws + 239075328);
  u16 *WfcT0hi = (u16 *)(ws + 243269632);
  u16 *WfcT0lo = (u16 *)(ws + 244318208);
  u16 *WxT1hi = (u16 *)(ws + 245366784);
  u16 *WxT1lo = (u16 *)(ws + 249561088);
  u16 *WfcT1hi = (u16 *)(ws + 253755392);
  u16 *WfcT1lo = (u16 *)(ws + 254803968);
  // done flags: carved from WxT regions, which are DEAD once their xz-GEMM
  // has run. Zeroed mid-stream (hipMemsetAsync is graph-capturable).
  int *done0 = (int *)(ws + 234881024);    // overlaps WxT0hi (512 KB used)
  int *done1 = (int *)(ws + 245366784);    // overlaps WxT1hi (512 KB used)

  // weight prepack (transpose + hi/lo split)
  k_packT<<<dim3(G4H / 32, DEMB / 32), dim3(32, 8), 0, stream>>>(Wx0, WxT0hi, WxT0lo, DEMB, G4H);
  k_packT<<<dim3(PDIM / 32, HDIM / 32), dim3(32, 8), 0, stream>>>(Wfc0, WfcT0hi, WfcT0lo, HDIM, PDIM);
  k_packT<<<dim3(G4H / 32, DEMB / 32), dim3(32, 8), 0, stream>>>(Wx1, WxT1hi, WxT1lo, DEMB, G4H);
  k_packT<<<dim3(PDIM / 32, HDIM / 32), dim3(32, 8), 0, stream>>>(Wfc1, WfcT1hi, WfcT1lo, HDIM, PDIM);
  // x0 = embed[tokens], hi/lo split  (rows m = b*T + t)
  k_gather_pack<<<4096, 256, 0, stream>>>(tokens, embed, x1hi, x1lo);

  // xz0 = x0 @ Wx0 + b0  -> bf16
  k_gemm<0><<<dim3(128 * 32), 256, 0, stream>>>(x1hi, x1lo, WxT0hi, WxT0lo, b0, xz, nullptr,
                                                16384, G4H, DEMB);
  // WxT0 now dead -> zero done0 in its place
  hipMemsetAsync(done0, 0, SEQT * 256 * sizeof(int), stream);
  // layer-0 recurrence (xz rows m = b*T + t)
  {
    const u16 *a0 = xz; const float *a1 = Wh0; u16 *a2 = hhi; u16 *a3 = hlo; int *a4 = done0; int a5 = 0;
    void *args[] = {&a0, &a1, &a2, &a3, &a4, &a5};
    hipError_t e = hipLaunchCooperativeKernel((void *)k_recur, dim3(NWGR), dim3(256), args, 0, stream);
    if (e != hipSuccess) fprintf(stderr, "coop launch L0 failed: %d\n", (int)e);
  }
  // x1 = h0 @ Wfc0 + bfc0 -> hi/lo planes (rows m = t*32 + b)
  k_gemm<1><<<dim3(128 * 4), 256, 0, stream>>>(hhi, hlo, WfcT0hi, WfcT0lo, bfc0, x1hi, x1lo,
                                               16384, PDIM, HDIM);
  // xz1 = x1 @ Wx1 + b1 -> bf16
  k_gemm<0><<<dim3(128 * 32), 256, 0, stream>>>(x1hi, x1lo, WxT1hi, WxT1lo, b1, xz, nullptr,
                                                16384, G4H, DEMB);
  // WxT1 now dead -> zero done1 in its place
  hipMemsetAsync(done1, 0, SEQT * 256 * sizeof(int), stream);
  // layer-1 recurrence (xz rows m = t*32 + b)
  {
    const u16 *a0 = xz; const float *a1 = Wh1; u16 *a2 = hhi; u16 *a3 = hlo; int *a4 = done1; int a5 = 1;
    void *args[] = {&a0, &a1, &a2, &a3, &a4, &a5};
    hipError_t e = hipLaunchCooperativeKernel((void *)k_recur, dim3(NWGR), dim3(256), args, 0, stream);
    if (e != hipSuccess) fprintf(stderr, "coop launch L1 failed: %d\n", (int)e);
  }
  // out = h1 @ Wfc1 + bfc1 -> f32, scattered to (B,T,P)
  k_gemm<2><<<dim3(128 * 4), 256, 0, stream>>>(hhi, hlo, WfcT1hi, WfcT1lo, bfc1, d_out, nullptr,
                                               16384, PDIM, HDIM);
}